// Round 9
// baseline (145.954 us; speedup 1.0000x reference)
//
#include <hip/hip_runtime.h>
#include <hip/hip_bf16.h>
#include <cstdint>

#define NV 64000      // B*N nodes
#define DD 64         // hidden dim
#define FF 3          // input features
#define NE 1000000    // edges
#define BB 32         // batch (graphs)
#define SS 50         // timesteps
#define NN 2000       // nodes per graph
#define PCH 16        // pooling chunks per graph
#define KB 1000       // coarse buckets (dst >> 6), 64 dsts each
#define CAP 1536      // records per bucket region (mean 1000, +17 sigma)
#define NBLKA 250     // partition blocks
#define EPB (NE / NBLKA)  // 4000 edges per partition block
#define INVALID 0xFFFFFFFFu

// ---------------------------------------------------------------------------
// Fused setup: zero gcur + int64-vs-int32 detection.
// ---------------------------------------------------------------------------
__global__ __launch_bounds__(256) void setup_kernel(const int* __restrict__ ei,
                                                    int* __restrict__ flag,
                                                    int* __restrict__ gcur) {
    int i = blockIdx.x * 256 + threadIdx.x;
    if (i < KB) gcur[i] = 0;
    if (blockIdx.x == 0) {
        __shared__ int nz;
        if (threadIdx.x == 0) nz = 0;
        __syncthreads();
        int local = 0;
        for (int k = threadIdx.x; k < 4096; k += 256)
            local |= (ei[2 * k + 1] != 0);
        if (local) atomicOr(&nz, 1);
        __syncthreads();
        if (threadIdx.x == 0) *flag = (nz == 0) ? 1 : 0;
    }
}

// ---------------------------------------------------------------------------
// Partition edges into KB coarse bucket regions as packed 4B records
// (src<<6)|(dst&63). Single edge-list read; records staged in LDS.
// ---------------------------------------------------------------------------
__global__ __launch_bounds__(256) void part_kernel(const int* __restrict__ ei32,
                                                   const int* __restrict__ flag,
                                                   int* __restrict__ gcur,
                                                   unsigned* __restrict__ parts) {
    __shared__ unsigned recs[EPB];   // 16 KB
    __shared__ int cnt[KB];          // 4 KB
    __shared__ int cur[KB];          // 4 KB
    const long long* ei64 = (const long long*)ei32;
    const int is64 = *flag;
    int t = threadIdx.x;
    int e0 = blockIdx.x * EPB;
    for (int i = t; i < KB; i += 256) cnt[i] = 0;
    __syncthreads();
    for (int i = t; i < EPB; i += 256) {
        int e = e0 + i;
        int s, d;
        if (is64) { s = (int)ei64[e]; d = (int)ei64[NE + e]; }
        else      { s = ei32[e];      d = ei32[NE + e]; }
        bool ok = (unsigned)s < NV && (unsigned)d < NV;
        recs[i] = ok ? (((unsigned)s << 16) | (unsigned)d) : INVALID;
        if (ok) atomicAdd(&cnt[d >> 6], 1);
    }
    __syncthreads();
    for (int b = t; b < KB; b += 256) {
        int c = cnt[b];
        cur[b] = (c > 0) ? atomicAdd(&gcur[b], c) : 0;
    }
    __syncthreads();
    for (int i = t; i < EPB; i += 256) {
        unsigned r = recs[i];
        if (r != INVALID) {
            int d = (int)(r & 0xFFFFu);
            int b = d >> 6;
            int pos = atomicAdd(&cur[b], 1);
            if (pos < CAP)
                parts[(size_t)b * CAP + pos] = ((r >> 16) << 6) | (unsigned)(d & 63);
        }
    }
}

// ---------------------------------------------------------------------------
// Per-bucket LDS counting sort -> beg/end + dinv; sorted src ids in place.
// ---------------------------------------------------------------------------
__global__ __launch_bounds__(256) void bsort_kernel(unsigned* __restrict__ parts,
                                                    const int* __restrict__ gcur,
                                                    int* __restrict__ beg,
                                                    int* __restrict__ end,
                                                    float* __restrict__ dinv) {
    __shared__ unsigned recs[CAP];
    __shared__ int srt[CAP];
    __shared__ int cnt64[64];
    __shared__ int pref[64];
    __shared__ int cur[64];
    int b = blockIdx.x, t = threadIdx.x;
    int cnt = min(gcur[b], CAP);
    unsigned* p = parts + (size_t)b * CAP;
    if (t < 64) cnt64[t] = 0;
    __syncthreads();
    for (int i = t; i < cnt; i += 256) {
        unsigned r = p[i];
        recs[i] = r;
        atomicAdd(&cnt64[r & 63u], 1);
    }
    __syncthreads();
    if (t < 64) pref[t] = cnt64[t];
    __syncthreads();
    #pragma unroll
    for (int off = 1; off < 64; off <<= 1) {
        int v = (t < 64 && t >= off) ? pref[t - off] : 0;
        __syncthreads();
        if (t < 64) pref[t] += v;
        __syncthreads();
    }
    if (t < 64) {
        int ex = pref[t] - cnt64[t];
        cur[t] = ex;
        int node = (b << 6) + t;
        beg[node] = b * CAP + ex;
        end[node] = b * CAP + ex + cnt64[t];
        dinv[node] = rsqrtf((float)(cnt64[t] + 1));
    }
    __syncthreads();
    for (int i = t; i < cnt; i += 256) {
        unsigned r = recs[i];
        int pos = atomicAdd(&cur[r & 63u], 1);
        srt[pos] = (int)(r >> 6);
    }
    __syncthreads();
    for (int i = t; i < cnt; i += 256) p[i] = (unsigned)srt[i];
}

// p0[node*3+f] = dinv[node] * mean over S of x[b][s][n][f]
__global__ void tmean_kernel(const float* __restrict__ x, const float* __restrict__ dinv,
                             float* __restrict__ p0) {
    int tid = blockIdx.x * blockDim.x + threadIdx.x;
    if (tid >= NV * FF) return;
    int nf = tid % (NN * FF);
    int b  = tid / (NN * FF);
    const float* xp = x + (size_t)b * SS * NN * FF + nf;
    float acc = 0.f;
    #pragma unroll
    for (int s = 0; s < SS; ++s) acc += xp[(size_t)s * NN * FF];
    int node = tid / 3;
    p0[tid] = dinv[node] * acc * (1.0f / SS);
}

// 3-dim aggregation: q04 = {sum p0[src] + p0[dst], dinv}. p0 L2-resident.
__global__ __launch_bounds__(256) void agg3_kernel(const int* __restrict__ beg,
                                                   const int* __restrict__ end,
                                                   const unsigned* __restrict__ srcs,
                                                   const float* __restrict__ p0,
                                                   const float* __restrict__ dinv,
                                                   float4* __restrict__ q04) {
    int node = blockIdx.x * 256 + threadIdx.x;
    if (node >= NV) return;
    int e = beg[node], en = end[node];
    float a0 = p0[node * 3 + 0], a1 = p0[node * 3 + 1], a2 = p0[node * 3 + 2];
    for (; e + 2 <= en; e += 2) {
        int s0 = srcs[e] * 3, s1 = srcs[e + 1] * 3;
        float u0 = p0[s0], u1 = p0[s0 + 1], u2 = p0[s0 + 2];
        float w0 = p0[s1], w1 = p0[s1 + 1], w2 = p0[s1 + 2];
        a0 += u0 + w0; a1 += u1 + w1; a2 += u2 + w2;
    }
    for (; e < en; ++e) {
        int s = srcs[e] * 3;
        a0 += p0[s]; a1 += p0[s + 1]; a2 += p0[s + 2];
    }
    q04[node] = make_float4(a0, a1, a2, dinv[node]);
}

// p1 = dinv * relu(dinv*(q0@W1) + b1), one wave per node (q04 broadcast read).
__global__ void trans1_kernel(const float4* __restrict__ q04,
                              const float* __restrict__ W1, const float* __restrict__ b1,
                              float* __restrict__ p1) {
    int tid = blockIdx.x * blockDim.x + threadIdx.x;  // NV*DD
    if (tid >= NV * DD) return;
    int node = tid >> 6, d = tid & 63;
    float4 q = q04[node];
    float h = fmaf(q.w, fmaf(q.x, W1[d], fmaf(q.y, W1[64 + d], q.z * W1[128 + d])), b1[d]);
    p1[tid] = q.w * fmaxf(h, 0.f);
}

// ---------------------------------------------------------------------------
// 64-dim aggregation, float4-per-lane: one wave per dst node; 16-lane group
// g handles edges e0+g, e0+g+4, ...; lane sub=(lane&15) gathers dims
// [4*sub,4*sub+4) as one dwordx4 (4 edges per vmem instruction). 2x unroll
// -> 2 outstanding 16B loads/lane. Butterfly (lane^16, lane^32) combines
// groups; group 0 holds the self-loop init and stores the 256B row.
// ---------------------------------------------------------------------------
__global__ __launch_bounds__(256) void agg64_kernel(const int* __restrict__ beg,
                                                    const int* __restrict__ end,
                                                    const unsigned* __restrict__ srcs,
                                                    const float* __restrict__ g,
                                                    float* __restrict__ raw) {
    int lane = threadIdx.x & 63;
    int node = (blockIdx.x * blockDim.x + threadIdx.x) >> 6;
    if (node >= NV) return;
    int grp = lane >> 4, sub = lane & 15;
    int e0 = beg[node], en = end[node];
    float4 acc;
    if (grp == 0) {
        acc = ((const float4*)(g + ((size_t)node << 6)))[sub];  // self loop
    } else {
        acc = make_float4(0.f, 0.f, 0.f, 0.f);
    }
    int e = e0 + grp;
    for (; e + 4 < en; e += 8) {
        int s0 = srcs[e], s1 = srcs[e + 4];
        float4 v0 = ((const float4*)(g + ((size_t)s0 << 6)))[sub];
        float4 v1 = ((const float4*)(g + ((size_t)s1 << 6)))[sub];
        acc.x += v0.x + v1.x; acc.y += v0.y + v1.y;
        acc.z += v0.z + v1.z; acc.w += v0.w + v1.w;
    }
    if (e < en) {
        int s = srcs[e];
        float4 v = ((const float4*)(g + ((size_t)s << 6)))[sub];
        acc.x += v.x; acc.y += v.y; acc.z += v.z; acc.w += v.w;
    }
    // combine the 4 groups (sub preserved under ^16/^32)
    acc.x += __shfl_xor(acc.x, 16); acc.y += __shfl_xor(acc.y, 16);
    acc.z += __shfl_xor(acc.z, 16); acc.w += __shfl_xor(acc.w, 16);
    acc.x += __shfl_xor(acc.x, 32); acc.y += __shfl_xor(acc.y, 32);
    acc.z += __shfl_xor(acc.z, 32); acc.w += __shfl_xor(acc.w, 32);
    if (grp == 0)
        ((float4*)(raw + ((size_t)node << 6)))[sub] = acc;
}

// h2 = relu(dinv*(q1@W2) + b2). W2 + 4 q1-rows staged in LDS.
__global__ __launch_bounds__(256) void trans2_kernel(const float* __restrict__ q1,
                                                     const float* __restrict__ dinv,
                                                     const float* __restrict__ b2,
                                                     const float* __restrict__ W2,
                                                     float* __restrict__ h2) {
    __shared__ float W2s[64 * 64];
    __shared__ float rows[4 * 64];
    int t = threadIdx.x;
    for (int i = t; i < 64 * 64; i += 256) W2s[i] = W2[i];
    int base = blockIdx.x * 256;
    int node0 = base >> 6;
    rows[t] = q1[base + t];
    __syncthreads();
    int sub = t >> 6, d = t & 63;
    const float* r = &rows[sub * 64];
    float acc = 0.f;
    #pragma unroll 8
    for (int k = 0; k < 64; ++k) acc += r[k] * W2s[k * 64 + d];
    float v = dinv[node0 + sub] * acc + b2[d];
    h2[base + t] = v > 0.f ? v : 0.f;
}

// --- Two-phase pooling (h2 already relu'd) ---
__global__ __launch_bounds__(256) void pool_part_kernel(const float* __restrict__ h2,
                                                        float* __restrict__ partials) {
    __shared__ float part[4][64];
    int blk = blockIdx.x;
    int b = blk / PCH, c = blk % PCH;
    int t = threadIdx.x;
    int d = t & 63, p = t >> 6;
    const int CHN = NN / PCH;  // 125
    int n0 = b * NN + c * CHN;
    float acc = 0.f;
    for (int n = p; n < CHN; n += 4)
        acc += h2[((size_t)(n0 + n) << 6) + d];
    part[p][d] = acc;
    __syncthreads();
    if (t < 64) {
        partials[(size_t)blk * 64 + t] =
            part[0][t] + part[1][t] + part[2][t] + part[3][t];
    }
}

__global__ __launch_bounds__(64) void pool_finish_kernel(const float* __restrict__ partials,
                                                         const float* __restrict__ Wh,
                                                         const float* __restrict__ bh,
                                                         float* __restrict__ out) {
    __shared__ float pooled[64];
    int b = blockIdx.x;
    int t = threadIdx.x;
    float s = 0.f;
    #pragma unroll
    for (int c = 0; c < PCH; ++c)
        s += partials[((size_t)b * PCH + c) * 64 + t];
    pooled[t] = s * (1.0f / NN);
    __syncthreads();
    if (t < 2) {
        float o = bh[t];
        #pragma unroll 16
        for (int k = 0; k < 64; ++k) o += pooled[k] * Wh[k * 2 + t];
        out[b * 2 + t] = o;
    }
}

extern "C" void kernel_launch(void* const* d_in, const int* in_sizes, int n_in,
                              void* d_out, int out_size, void* d_ws, size_t ws_size,
                              hipStream_t stream) {
    const float* x  = (const float*)d_in[0];
    const int*   ei = (const int*)d_in[1];
    const float* W1 = (const float*)d_in[2];
    const float* b1 = (const float*)d_in[3];
    const float* W2 = (const float*)d_in[4];
    const float* b2 = (const float*)d_in[5];
    const float* Wh = (const float*)d_in[6];
    const float* bh = (const float*)d_in[7];
    float* out = (float*)d_out;

    float* ws   = (float*)d_ws;
    float* bufA = ws;                          // NV*DD  (p1, then h2)
    float* bufB = bufA + (size_t)NV * DD;      // NV*DD  (q1)
    float* p0   = bufB + (size_t)NV * DD;      // NV*FF
    float4* q04 = (float4*)(p0 + (size_t)NV * FF);  // NV
    float* dinv = (float*)(q04 + NV);          // NV
    float* partials = dinv + NV;               // BB*PCH*64
    unsigned* parts = (unsigned*)(partials + BB * PCH * 64);  // KB*CAP
    int*   beg  = (int*)(parts + (size_t)KB * CAP);           // NV
    int*   end  = beg + NV;                    // NV
    int*   gcur = end + NV;                    // KB
    int*   flag = gcur + KB;                   // 1

    // --- Build bucketed, per-bucket-sorted edge structure ---
    setup_kernel<<<4, 256, 0, stream>>>(ei, flag, gcur);
    part_kernel<<<NBLKA, 256, 0, stream>>>(ei, flag, gcur, parts);
    bsort_kernel<<<KB, 256, 0, stream>>>(parts, gcur, beg, end, dinv);

    // --- p0 = dinv * temporal-mean(x) ---
    tmean_kernel<<<(NV * FF + 255) / 256, 256, 0, stream>>>(x, dinv, p0);

    // --- Layer 1 aggregation (3-dim gather) -> q04 = {q0, dinv} ---
    agg3_kernel<<<(NV + 255) / 256, 256, 0, stream>>>(beg, end, parts, p0, dinv, q04);

    // --- Layer 1 transform (once per node) ---
    trans1_kernel<<<NV * DD / 256, 256, 0, stream>>>(q04, W1, b1, bufA);

    // --- Layer 2 aggregation (float4-per-lane, 4 edges/instr) ---
    agg64_kernel<<<NV * 64 / 256, 256, 0, stream>>>(beg, end, parts, bufA, bufB);

    // --- Layer-2 transform ---
    trans2_kernel<<<NV * DD / 256, 256, 0, stream>>>(bufB, dinv, b2, W2, bufA);

    // --- Pool + head (two-phase) ---
    pool_part_kernel<<<BB * PCH, 256, 0, stream>>>(bufA, partials);
    pool_finish_kernel<<<BB, 64, 0, stream>>>(partials, Wh, bh, out);
}